// Round 7
// baseline (392.244 us; speedup 1.0000x reference)
//
#include <hip/hip_runtime.h>
#include <hip/hip_bf16.h>
#include <math.h>

// B=8 T=2048 E=512 H=8 | NQ_H=4 NL=2 | NQ_F=8 FFN=2048
// Quantum circuits collapse to: qout_q = cos(x_q)*A_q - sin(x_q)*B_q (per-head/FFN consts).
// Round 14: k2_attn 53us, MfmaUtil 28%: per-ec staging (48KB GLL16) immediately hits
// syncthreads -> vmcnt(0) drain with ZERO cover (m97 pattern, ~875cyc L2 service
// serialized vs ~400cyc compute). -> T3 minimum 2-phase: BK=32, double-buffered Q/K
// (Qc 2x8KB, Ks 2x16KB, live 66KB; LDS stays 77.8KB via epilogue overlay -> 2 blk/CU).
// Per ec: issue 6 GLL16 for ec+1 FIRST, then frags + 32 MFMA (setprio), ONE barrier.
// Also fused k2_merge into k3's Qs stage (4-partial merge + trig inline) -- one less
// launch + q32b round-trip gone.

#define B_   8
#define T_   2048
#define E_   512

typedef __attribute__((ext_vector_type(8))) short bf16x8;
typedef __attribute__((ext_vector_type(4))) short bf16x4;
typedef __attribute__((ext_vector_type(4))) float f32x4;

#define GLL16(g, l) __builtin_amdgcn_global_load_lds((const __attribute__((address_space(1))) void*)(g), (__attribute__((address_space(3))) void*)(l), 16, 0, 0)

__device__ inline unsigned short f2bf(float f){
  union { float f; unsigned u; } v; v.f = f;
  unsigned r = v.u + 0x7fff + ((v.u >> 16) & 1);   // RTNE
  return (unsigned short)(r >> 16);
}

// ------------------------------------------- K0 (parallel): circuits + wo32b pack
__global__ __launch_bounds__(256) void k0_setup(const float* __restrict__ hp,
                         const float* __restrict__ fp,
                         const float* __restrict__ wo, float* __restrict__ cAB,
                         unsigned short* __restrict__ wo32b) {
  int t = threadIdx.x, bi = blockIdx.x;
  if (bi > 0) {                      // blocks 1..16: pack wo32b bf16 (coalesced)
    int gid = (bi-1)*256 + t;        // 4096 = 512 rows x 8 groups of 4 cols
    int e = gid >> 3, c4 = gid & 7;  // wo cols c4*64 .. c4*64+3 are contiguous
    float4 v = *(const float4*)(wo + (size_t)e*512 + c4*64);
    unsigned short h[4] = { f2bf(v.x), f2bf(v.y), f2bf(v.z), f2bf(v.w) };
    *(unsigned long long*)(wo32b + (size_t)e*32 + c4*4) = *(unsigned long long*)h;
    return;
  }
  // ---- block 0: FFN 8-qubit circuit, one amplitude per thread ----
  __shared__ float fst[256], tmp[256], ra[256], rb[256];
  fst[t] = (t == 0) ? 1.f : 0.f;
  __syncthreads();
  #pragma unroll
  for (int q = 0; q < 8; ++q) {      // RY layer (params row 0)
    int str = 1 << (7-q);
    float th = 0.5f * fp[q];
    float c = cosf(th), s = sinf(th);
    float self = fst[t], part = fst[t ^ str];
    float nv = (t & str) ? (c*self + s*part) : (c*self - s*part);
    __syncthreads();
    tmp[t] = nv;
    __syncthreads();
    fst[t] = tmp[t];
    __syncthreads();
  }
  #pragma unroll
  for (int g = 0; g < 8; ++g) {      // CNOT chain + ring
    int ctrl = (g < 7) ? g : 7, tgt = (g < 7) ? g+1 : 0;
    int cs = 1 << (7-ctrl), tsr = 1 << (7-tgt);
    float nv = fst[(t & cs) ? (t ^ tsr) : t];
    __syncthreads();
    fst[t] = nv;
    __syncthreads();
  }
  #pragma unroll
  for (int q = 0; q < 8; ++q) {      // <Z_q>, <X_q>
    int str = 1 << (7-q);
    float a = fst[t]*fst[t] * ((t & str) ? -1.f : 1.f);
    float b = fst[t]*fst[t ^ str];
    ra[t] = a; rb[t] = b;
    __syncthreads();
    for (int off = 128; off > 0; off >>= 1){
      if (t < off){ ra[t] += ra[t+off]; rb[t] += rb[t+off]; }
      __syncthreads();
    }
    if (t == 0){ cAB[64+q] = ra[0]; cAB[72+q] = rb[0]; }
    __syncthreads();
  }
  // ---- per-head 4-qubit circuits: 8 parallel threads, 16 amps in registers ----
  if (t < 8) {
    float st[16];
    #pragma unroll
    for (int i=0;i<16;i++) st[i]=0.f;
    st[0]=1.f;
    for (int l=0;l<2;l++){
      for (int q=0;q<4;q++){
        float th = 0.5f*hp[t*8 + l*4 + q];
        float c = cosf(th), s = sinf(th);
        int str = 1<<(3-q);
        for (int i=0;i<16;i++) if (!(i & str)) {
          float s0=st[i], s1=st[i|str];
          st[i]     = c*s0 - s*s1;
          st[i|str] = s*s0 + c*s1;
        }
      }
      for (int q=0;q<4;q++){
        int ctrl = (q<3)? q : 3, tgt = (q<3)? q+1 : 0;
        int cs = 1<<(3-ctrl), tsr = 1<<(3-tgt);
        for (int i=0;i<16;i++) if ((i&cs) && !(i&tsr)) {
          float tt = st[i]; st[i]=st[i|tsr]; st[i|tsr]=tt;
        }
      }
    }
    for (int q=0;q<4;q++){
      int str = 1<<(3-q);
      float A=0.f, Bv=0.f;
      for (int i=0;i<16;i++){
        A  += st[i]*st[i] * ((i&str)? -1.f : 1.f);
        Bv += st[i]*st[i^str];
      }
      cAB[t*4+q]    = A;
      cAB[32+t*4+q] = Bv;
    }
  }
}

// -------------------------- merged casts to bf16 (xb | wqkb, w2b, wv32b)
__global__ __launch_bounds__(256) void kc_cast(const float* __restrict__ x,
                     const float* __restrict__ wq, const float* __restrict__ wk,
                     const float* __restrict__ w2, const float* __restrict__ wv,
                     unsigned short* __restrict__ xb, unsigned short* __restrict__ wqkb,
                     unsigned short* __restrict__ w2b, unsigned short* __restrict__ wv32b){
  int bi = blockIdx.x;
  if (bi < 4096) {                                 // x -> xb: 1048576 chunks of 8
    int i = bi*256 + threadIdx.x;
    const float4* p = (const float4*)x + (size_t)i*2;
    float4 a = p[0], b = p[1];
    union { unsigned short h[8]; uint4 u; } o;
    o.h[0]=f2bf(a.x); o.h[1]=f2bf(a.y); o.h[2]=f2bf(a.z); o.h[3]=f2bf(a.w);
    o.h[4]=f2bf(b.x); o.h[5]=f2bf(b.y); o.h[6]=f2bf(b.z); o.h[7]=f2bf(b.w);
    ((uint4*)xb)[i] = o.u;
    return;
  }
  int i = (bi-4096)*256 + threadIdx.x;             // 198656 chunks of 8
  const float* src; unsigned short* dst; float s = 1.f;
  if (i < 65536){
    int row = i >> 6, c8 = (i & 63)*8;
    if (row < 512){ src = wq + (size_t)row*512 + c8; s = 0.044194173824159216f; } // fold 1/sqrt(E)
    else          { src = wk + (size_t)(row-512)*512 + c8; }
    dst = wqkb + (size_t)row*512 + c8;
  } else if (i < 196608){
    int j = i - 65536;
    src = w2 + (size_t)j*8; dst = w2b + (size_t)j*8;
  } else {
    int j = i - 196608;                            // 2048 chunks: wv32b [32][512]
    int r = j >> 6, c8 = (j & 63)*8;               // channel r = head*4 + qubit
    src = wv + (size_t)((r>>2)*64 + (r&3))*512 + c8;
    dst = wv32b + (size_t)r*512 + c8;
  }
  float4 a = *(const float4*)src, b = *(const float4*)(src+4);
  union { unsigned short h[8]; uint4 u; } o;
  o.h[0]=f2bf(a.x*s); o.h[1]=f2bf(a.y*s); o.h[2]=f2bf(a.z*s); o.h[3]=f2bf(a.w*s);
  o.h[4]=f2bf(b.x*s); o.h[5]=f2bf(b.y*s); o.h[6]=f2bf(b.z*s); o.h[7]=f2bf(b.w*s);
  *(uint4*)dst = o.u;
}

// ------------- m97-style MFMA GEMM: C = A (MxK) * Bw^T (NxK), XCD-aware swizzle
// 1-D grid of GX*GM blocks; same-XCD blocks (lin%8) share A m-tiles via L2.
template<int K, int LDC, bool OUTBF, int GX, int GM>
__global__ __launch_bounds__(256,2) void gemm_bt(
    const unsigned short* __restrict__ A, const unsigned short* __restrict__ Bw,
    void* __restrict__ C, int m_base){
  __shared__ __align__(16) char sm[16384];
  char* As = sm; char* Bs = sm + 8192;             // [128][32] bf16, 64B rows, xor-swizzled
  int t = threadIdx.x, w = t>>6, l = t&63;
  int lr = l&15, quad = l>>4;
  int lin = blockIdx.x;
  int n0 = ((lin >> 3) % GX) * 128;
  int m0 = ((lin & 7) * (GM/8) + lin / (8*GX)) * 128;
  int wr = (w>>1)*64, wc = (w&1)*64;
  f32x4 acc[4][4] = {};
  for (int k0 = 0; k0 < K; k0 += 32){
    __syncthreads();
    #pragma unroll
    for (int c = 0; c < 2; ++c){
      int ch = c*256 + t, row = ch>>2, sw = ch&3, lc = sw ^ ((row>>1)&3);
      GLL16(A  + (size_t)(m0+row)*K + k0 + lc*8, As + c*4096 + w*1024);
      GLL16(Bw + (size_t)(n0+row)*K + k0 + lc*8, Bs + c*4096 + w*1024);
    }
    __syncthreads();
    bf16x8 af[4], bg[4];
    #pragma unroll
    for (int i=0;i<4;++i){
      int ra = wr + i*16 + lr;
      af[i] = *(const bf16x8*)(As + ra*64 + (quad ^ ((ra>>1)&3))*16);
      int rb = wc + i*16 + lr;
      bg[i] = *(const bf16x8*)(Bs + rb*64 + (quad ^ ((rb>>1)&3))*16);
    }
    #pragma unroll
    for (int i=0;i<4;++i)
      #pragma unroll
      for (int j=0;j<4;++j)
        acc[i][j] = __builtin_amdgcn_mfma_f32_16x16x32_bf16(af[i], bg[j], acc[i][j], 0,0,0);
  }
  #pragma unroll
  for (int i=0;i<4;++i)
    #pragma unroll
    for (int j=0;j<4;++j)
      #pragma unroll
      for (int r=0;r<4;++r){
        size_t row = (size_t)(m_base + m0 + wr + i*16 + quad*4 + r);
        int col = n0 + wc + j*16 + lr;
        if constexpr (OUTBF) ((unsigned short*)C)[row*LDC + col] = f2bf(acc[i][j][r]);
        else                 ((float*)C)[row*LDC + col] = acc[i][j][r];
      }
}

// ---- K1v (MFMA): v32t[b][c][s] = bf16(xb @ wv32b^T), skinny N=32 GEMM.
__global__ __launch_bounds__(256) void k1_v32m(const unsigned short* __restrict__ xb,
    const unsigned short* __restrict__ wv32b, unsigned short* __restrict__ v32t){
  __shared__ __align__(16) char sm1[98304];     // Xs 64KB + Ws 32KB
  char* Xs = sm1; char* Ws = sm1 + 65536;
  int t = threadIdx.x, w = t>>6, l = t&63, lr = l&15, quad = l>>4;
  int m0 = blockIdx.x * 64;
  #pragma unroll
  for (int i=0;i<16;++i){                       // stage 16 X subtiles [64][32]
    int p = i*256 + t, ks = p>>8, c2 = p&255, row = c2>>2, swp = c2&3;
    int lc = swp ^ ((row>>1)&3);
    GLL16(xb + (size_t)(m0+row)*512 + ks*32 + lc*8, Xs + (p>>6)*1024);
  }
  #pragma unroll
  for (int i=0;i<8;++i){                        // stage 16 W subtiles [32][32]
    int p = i*256 + t, ks = p>>7, c2 = p&127, row = c2>>2, swp = c2&3;
    int lc = swp ^ ((row>>1)&3);
    GLL16(wv32b + (size_t)row*512 + ks*32 + lc*8, Ws + (p>>6)*1024);
  }
  __syncthreads();
  f32x4 acc[2] = {};
  #pragma unroll
  for (int ks=0; ks<16; ++ks){
    int xrow = w*16 + lr;
    bf16x8 bq = *(const bf16x8*)(Xs + ks*4096 + xrow*64 + (quad ^ ((xrow>>1)&3))*16);
    #pragma unroll
    for (int ni=0; ni<2; ++ni){
      int wrow = ni*16 + lr;
      bf16x8 af = *(const bf16x8*)(Ws + ks*2048 + wrow*64 + (quad ^ ((wrow>>1)&3))*16);
      acc[ni] = __builtin_amdgcn_mfma_f32_16x16x32_bf16(af, bq, acc[ni], 0,0,0);
    }
  }
  int bb = m0 >> 11, sbase = (m0 & 2047) + w*16 + lr;
  #pragma unroll
  for (int ni=0; ni<2; ++ni)
    #pragma unroll
    for (int r=0; r<4; ++r){
      int c = ni*16 + quad*4 + r;
      v32t[((size_t)(bb*32 + c))*2048 + sbase] = f2bf(acc[ni][r]);
    }
}

// ------ K2: MFMA flash attention (S^T trick), QBLK=128, BK=32 double-buffered
// 2-phase staging (issue ec+1 before ec's MFMA), one barrier/ec. KV-split x4.
__global__ __launch_bounds__(256,2) void k2_attn(
    const unsigned short* __restrict__ qkb, const unsigned short* __restrict__ v32t,
    float* __restrict__ Opart, float* __restrict__ mlb){
  __shared__ __align__(16) char sm[77824];
  char* Qc  = sm;            // 2 bufs x [128][32] bf16 swizzled (16 KB)
  char* Ks  = sm + 16384;    // 2 bufs x [256][32] bf16 swizzled (32 KB)
  char* Vts = sm + 49152;    // [32][256+8] bf16, 528B rows (16.5 KB)
  float* OtL = (float*)sm;           // merge overlay: [4][128][36] f32 (73728 B)
  float* mL  = (float*)(sm + 73728); // [4][128]
  float* lL  = (float*)(sm + 75776); // [4][128]

  int t = threadIdx.x, w = t>>6, l = t&63;
  int lr = l & 15, quad = l >> 4;
  int lin = blockIdx.x;
  int b = lin & 7;                   // one batch per XCD
  int m0 = ((lin >> 3) & 15) * 128;
  int half = lin >> 7;               // KV quarter
  size_t bT = (size_t)b*2048;
  const char* qbase = (const char*)qkb + (bT + m0)*2048;       // q cols 0-511 (pre-scaled)
  const char* vbase = (const char*)v32t + (size_t)b*32*4096;

  f32x4 Ot[2][8] = {};
  float mold[8], lsum[8];
  #pragma unroll
  for (int qj=0;qj<8;++qj){ mold[qj] = -1e30f; lsum[qj] = 0.f; }

  for (int st = 0; st < 2; ++st){
    int s0 = (half*2 + st)*256;
    const char* kbase = (const char*)qkb + (bT + s0)*2048 + 1024; // k cols 512-1023
    __syncthreads();                 // prior readers of Vts/bufs done
    { // stage V^T tile [32 vcols][256 scols]
      int j = t>>3, seg = t&7;
      const uint4* vs = (const uint4*)(vbase + (size_t)j*4096 + (s0 + seg*32)*2);
      uint4* vd = (uint4*)(Vts + j*528 + seg*64);
      vd[0]=vs[0]; vd[1]=vs[1]; vd[2]=vs[2]; vd[3]=vs[3];
    }
    { // prologue: stage ec=0 -> buf0
      #pragma unroll
      for (int c = 0; c < 2; ++c){
        int ch = c*256 + t, row = ch>>2, sw = ch&3, lc = sw ^ ((row>>1)&3);
        GLL16(qbase + (size_t)row*2048 + lc*16, Qc + c*4096 + w*1024);
      }
      #pragma unroll
      for (int rd = 0; rd < 4; ++rd){
        int ch = rd*256 + t, row = ch>>2, sw = ch&3, lc = sw ^ ((row>>1)&3);
        GLL16(kbase + (size_t)row*2048 + lc*16, Ks + rd*4096 + w*1024);
      }
    }
    f32x4 acc[4][8] = {};   // S^T tile: sc = w*64+si*16+quad*4+r, qr = qj*16+lr
    __syncthreads();        // buf0 + V ready
    for (int ec = 0; ec < 16; ++ec){   // BK=32: 16 iterations over the 512 K-dim
      int cur = ec&1, nxt = cur^1;
      if (ec < 15){                    // issue next-step staging FIRST (2-phase)
        #pragma unroll
        for (int c = 0; c < 2; ++c){
          int ch = c*256 + t, row = ch>>2, sw = ch&3, lc = sw ^ ((row>>1)&3);
          GLL16(qbase + (size_t)row*2048 + (ec+1)*64 + lc*16, Qc + nxt*8192 + c*4096 + w*1024);
        }
        #pragma unroll
        for (int rd = 0; rd < 4; ++rd){
          int ch = rd*256 + t, row = ch>>2, sw = ch&3, lc = sw ^ ((row>>1)&3);
          GLL16(kbase + (size_t)row*2048 + (ec+1)*64 + lc*16, Ks + nxt*16384 + rd*4096 + w*1024);
        }
      }
      bf16x8 af[4];
      #pragma unroll
      for (int si = 0; si < 4; ++si){
        int row = w*64 + si*16 + lr;
        af[si] = *(const bf16x8*)(Ks + cur*16384 + row*64 + (quad ^ ((row>>1)&3))*16);
      }
      #pragma unroll
      for (int qh = 0; qh < 2; ++qh){
        bf16x8 bq[4];
        #pragma unroll
        for (int jj = 0; jj < 4; ++jj){
          int row = (qh*4+jj)*16 + lr;
          bq[jj] = *(const bf16x8*)(Qc + cur*8192 + row*64 + (quad ^ ((row>>1)&3))*16);
        }
        __builtin_amdgcn_s_setprio(1);
        #pragma unroll
        for (int si = 0; si < 4; ++si)
          #pragma unroll
          for (int jj = 0; jj < 4; ++jj)   // S^T = K * Q^T
            acc[si][qh*4+jj] = __builtin_amdgcn_mfma_f32_16x16x32_bf16(af[si], bq[jj], acc[si][qh*4+jj], 0,0,0);
        __builtin_amdgcn_s_setprio(0);
      }
      __syncthreads();                 // nxt buffers landed; cur reads complete
    }
    // online softmax over sc (rows of S^T) + PV from registers
    bf16x4 aV[2][4];
    #pragma unroll
    for (int vt=0; vt<2; ++vt)
      #pragma unroll
      for (int si=0; si<4; ++si)
        aV[vt][si] = *(const bf16x4*)(Vts + (vt*16+lr)*528 + (w*64 + si*16 + quad*4)*2);
    #pragma unroll
    for (int qj=0; qj<8; ++qj){
      float mt = -1e30f;
      #pragma unroll
      for (int si=0; si<4; ++si)
        #pragma unroll
        for (int r=0;r<4;++r) mt = fmaxf(mt, acc[si][qj][r]);
      mt = fmaxf(mt, __shfl_xor(mt, 16));
      mt = fmaxf(mt, __shfl_xor(mt, 32));
      float mn = fmaxf(mold[qj], mt);
      float al = __expf(mold[qj] - mn);
      mold[qj] = mn;
      float rs = 0.f;
      #pragma unroll
      for (int si=0; si<4; ++si)
        #pragma unroll
        for (int r=0;r<4;++r){
          float p = __expf(acc[si][qj][r] - mn);
          acc[si][qj][r] = p; rs += p;
        }
      rs += __shfl_xor(rs, 16); rs += __shfl_xor(rs, 32);
      lsum[qj] = lsum[qj]*al + rs;
      Ot[0][qj] *= al; Ot[1][qj] *= al;
      #pragma unroll
      for (int si=0; si<4; ++si){
        bf16x4 pb;                                  // P^T in exact B-operand layout
        pb[0]=(short)f2bf(acc[si][qj][0]); pb[1]=(short)f2bf(acc[si][qj][1]);
        pb[2]=(short)f2bf(acc[si][qj][2]); pb[3]=(short)f2bf(acc[si][qj][3]);
        Ot[0][qj] = __builtin_amdgcn_mfma_f32_16x16x16bf16_1k(aV[0][si], pb, Ot[0][qj], 0,0,0);
        Ot[1][qj] = __builtin_amdgcn_mfma_f32_16x16x16bf16_1k(aV[1][si], pb, Ot[1][qj], 0,0,0);
      }
    }
  }
  // merge 4 per-wave partial streams -> unnormalized quarter-partials to global
  __syncthreads();
  #pragma unroll
  for (int qj=0; qj<8; ++qj){
    if (quad == 0){ mL[w*128 + qj*16 + lr] = mold[qj]; lL[w*128 + qj*16 + lr] = lsum[qj]; }
    *(f32x4*)(OtL + (size_t)(w*128 + qj*16 + lr)*36 + quad*4)      = Ot[0][qj];
    *(f32x4*)(OtL + (size_t)(w*128 + qj*16 + lr)*36 + 16 + quad*4) = Ot[1][qj];
  }
  __syncthreads();
  #pragma unroll
  for (int u=0; u<2; ++u){
    int qr = u*64 + (t>>2), vg = (t&3)*8;
    float M = -1e30f;
    #pragma unroll
    for (int w4=0; w4<4; ++w4) M = fmaxf(M, mL[w4*128+qr]);
    float L = 0.f; float o[8] = {};
    #pragma unroll
    for (int w4=0; w4<4; ++w4){
      float a = __expf(mL[w4*128+qr] - M);
      L += a * lL[w4*128+qr];
      const float* Op = OtL + (size_t)(w4*128+qr)*36 + vg;
      #pragma unroll
      for (int j=0;j<8;++j) o[j] += a*Op[j];
    }
    size_t tok = bT + m0 + qr;
    float* od = Opart + ((size_t)half*16384 + tok)*32 + vg;
    *(float4*)od     = make_float4(o[0],o[1],o[2],o[3]);
    *(float4*)(od+4) = make_float4(o[4],o[5],o[6],o[7]);
    if ((t&3) == 0){
      mlb[((size_t)half*16384 + tok)*2]     = M;
      mlb[((size_t)half*16384 + tok)*2 + 1] = L;
    }
  }
}

// ---- K3 (MFMA): x1 = LN(x + merge(Opart)@wo32b^T, g1,b1); fbuf = trig(x1[:, :8])
// k2_merge fused into the Qs stage: 4-partial softmax merge + circuit trig inline.
__global__ __launch_bounds__(256) void k3_proj_ln(const float* __restrict__ x,
    const float* __restrict__ Opart, const float* __restrict__ mlb,
    const unsigned short* __restrict__ wo32b,
    const float* __restrict__ g1, const float* __restrict__ b1,
    const float* __restrict__ cAB, float* __restrict__ x1, float* __restrict__ fbuf) {
  __shared__ __align__(16) char sm3[36224];
  char* Ws = sm3;                          // [512][32] bf16 swizzled, 32 KB
  char* Qs = sm3 + 32768;                  // [32][32] bf16 swizzled, 2 KB
  float* red1 = (float*)(sm3 + 34816);     // [4][32]
  float* red2 = (float*)(sm3 + 35328);     // [4][32]
  float* mm   = (float*)(sm3 + 35840);     // [32]
  float* rr   = (float*)(sm3 + 35968);     // [32]
  int t = threadIdx.x, w = t>>6, l = t&63, lr = l&15, quad = l>>4;
  int tok0 = blockIdx.x * 32;
  #pragma unroll
  for (int i=0;i<8;++i){                   // stage wo32b: 2048 uint4
    int g = t + i*256, row = g>>2, ch = g&3;
    uint4 v = ((const uint4*)wo32b)[g];
    *(uint4*)(Ws + row*64 + (ch ^ ((row>>1)&3))*16) = v;
  }
  { // fused merge: Qs[tok][col] = trig(softmax-merge of 4 Opart streams)
    int tokL = t>>3, cg = t&7;             // 32 tokens x 8 col-groups of 4
    size_t gt = (size_t)tok0 + tokL;
    float m[4], lv[4];
    #pragma unroll
    for (int h=0;h<4;++h){
      m[h]  = mlb[((size_t)h*16384 + gt)*2];
      lv[h] = mlb[((size_t)h*16384 + gt)*2 + 1];
    }
    float M = fmaxf(fmaxf(m[0],m[1]), fmaxf(m[2],m[3]));
    float a[4], L = 0.f;
    #pragma unroll
    for (int h=0;h<4;++h){ a[h] = __expf(m[h]-M); L += a[h]*lv[h]; }
    float inv = 1.f / L;
    float o[4] = {};
    #pragma unroll
    for (int h=0;h<4;++h){
      float4 v = *(const float4*)(Opart + ((size_t)h*16384 + gt)*32 + cg*4);
      o[0] += a[h]*v.x; o[1] += a[h]*v.y; o[2] += a[h]*v.z; o[3] += a[h]*v.w;
    }
    bf16x4 qv;
    #pragma unroll
    for (int j=0;j<4;++j){
      float ov = o[j] * inv;
      int cc = cg*4 + j;
      qv[j] = (short)f2bf(cosf(ov)*cAB[cc] - sinf(ov)*cAB[32+cc]);
    }
    *(bf16x4*)(Qs + tokL*64 + (((cg>>1) ^ ((tokL>>1)&3))<<4) + ((cg&1)<<3)) = qv;
  }
  __syncthreads();
  bf16x8 af[2], bf[8];
  #pragma unroll
  for (int i=0;i<2;++i){
    int m = i*16 + lr;
    af[i] = *(const bf16x8*)(Qs + m*64 + (quad ^ ((m>>1)&3))*16);
  }
  #pragma unroll
  for (int j=0;j<8;++j){
    int n = w*128 + j*16 + lr;
    bf[j] = *(const bf16x8*)(Ws + n*64 + (quad ^ ((n>>1)&3))*16);
  }
  f32x4 acc[2][8];
  #pragma unroll
  for (int i=0;i<2;++i)
    #pragma unroll
    for (int j=0;j<8;++j){
      f32x4 z = {0.f,0.f,0.f,0.f};
      acc[i][j] = __builtin_amdgcn_mfma_f32_16x16x32_bf16(af[i], bf[j], z, 0,0,0);
    }
  // residual add + row-sum accumulation
  float s1[2][4] = {}, s2[2][4] = {};
  #pragma unroll
  for (int i=0;i<2;++i)
    #pragma unroll
    for (int r=0;r<4;++r){
      int m = i*16 + quad*4 + r;
      const float* xrow = x + (size_t)(tok0+m)*512 + w*128 + lr;
      #pragma unroll
      for (int j=0;j<8;++j){
        float v = acc[i][j][r] + xrow[j*16];
        acc[i][j][r] = v;
        s1[i][r] += v; s2[i][r] += v*v;
      }
    }
  #pragma unroll
  for (int off=1; off<16; off<<=1){
    #pragma unroll
    for (int i=0;i<2;++i)
      #pragma unroll
      for (int r=0;r<4;++r){
        s1[i][r] += __shfl_xor(s1[i][r], off);
        s2[i][r] += __shfl_xor(s2[i][r], off);
      }
  }
  if (lr == 0){
    #pragma unroll
    for (int i=0;i<2;++i)
      #pragma unroll
      for (int r=0;r<4;++r){
        int m = i*16 + quad*4 + r;
        red1[w*32 + m] = s1[i][r];
        red2[w*32 + m] = s2[i][r];
      }
  }
  __syncthreads();
  if (t < 32){
    float a = red1[t] + red1[32+t] + red1[64+t] + red1[96+t];
    float bb = red2[t] + red2[32+t] + red2[64+t] + red2[96+t];
    float mean = a * (1.f/512.f);
    float var  = bb * (1.f/512.f) - mean*mean;
    mm[t] = mean; rr[t] = rsqrtf(var + 1e-5f);
  }
  __syncthreads();
  float g1v[8], b1v[8];
  #pragma unroll
  for (int j=0;j<8;++j){
    int n = w*128 + j*16 + lr;
    g1v[j] = g1[n]; b1v[j] = b1[n];
  }
  #pragma unroll
  for (int i=0;i<2;++i)
    #pragma unroll
    for (int r=0;r<4;++r){
      int m = i*16 + quad*4 + r;
      float mean = mm[m], rstd = rr[m];
      float* orow = x1 + (size_t)(tok0+m)*512 + w*128 + lr;
      #pragma unroll
      for (int j=0;j<8;++j){
        float nv = (acc[i][j][r]-mean)*rstd*g1v[j] + b1v[j];
        orow[j*16] = nv;
        if (w == 0 && j == 0 && lr < 8)
          fbuf[(size_t)(tok0+m)*8 + lr] = cosf(nv)*cAB[64+lr] - sinf(nv)*cAB[72+lr];
      }
    }
}

// ---- K4a4: Hb = bf16(relu(fbuf @ w1^T)) for an 8192-token half.
__global__ __launch_bounds__(256) void k4a4(const float* __restrict__ fbuf,
    const float* __restrict__ w1, unsigned short* __restrict__ Hb, int row0){
  __shared__ float w1s[16384];                // [2048][8] f32 linear, 64KB
  int t = threadIdx.x;
  #pragma unroll
  for (int i=0;i<16;++i){                     // coalesced stage: 4096 float4
    int p = i*256 + t;
    *(float4*)(w1s + (size_t)p*4) = *(const float4*)(w1 + (size_t)p*4);
  }
  __syncthreads();
  float wv[8][8];                             // rows 8t..8t+7 -> 64 VGPRs
  #pragma unroll
  for (int i=0;i<16;++i){
    float4 v = *(const float4*)(w1s + t*64 + i*4);
    wv[i>>1][(i&1)*4+0]=v.x; wv[i>>1][(i&1)*4+1]=v.y;
    wv[i>>1][(i&1)*4+2]=v.z; wv[i>>1][(i&1)*4+3]=v.w;
  }
  int tokL = blockIdx.x * 32;                 // local token base within the half
  #pragma unroll 2
  for (int u=0;u<32;++u){
    const float4* fp4 = (const float4*)(fbuf + (size_t)(row0 + tokL + u)*8);
    float4 fa = fp4[0], fb = fp4[1];
    union { unsigned short h[8]; uint4 q; } o;
    #pragma unroll
    for (int j=0;j<8;++j){
      float s = fa.x*wv[j][0] + fa.y*wv[j][1] + fa.z*wv[j][2] + fa.w*wv[j][3]
              + fb.x*wv[j][4] + fb.y*wv[j][5] + fb.z*wv[j][6] + fb.w*wv[j][7];
      o.h[j] = f2bf(fmaxf(s, 0.f));
    }
    *(uint4*)(Hb + (size_t)(tokL + u)*2048 + t*8) = o.q;
  }
}

// --------------------------------------------- K5: out = LN(x1 + out2, g2, b2)
__global__ __launch_bounds__(256) void k5_ln2(const float* __restrict__ x1,
    const float* __restrict__ g2, const float* __restrict__ b2,
    float* __restrict__ out) {
  int tok = blockIdx.x, t = threadIdx.x;
  __shared__ float rs1[4], rs2[4], mv[2];
  float vals[2], ssum=0.f, ssq=0.f;
  #pragma unroll
  for (int u=0;u<2;u++){
    int e = t + u*256;
    float s = x1[(size_t)tok*512 + e] + out[(size_t)tok*512 + e];
    vals[u]=s; ssum+=s; ssq+=s*s;
  }
  #pragma unroll
  for (int off=32; off>0; off>>=1){ ssum += __shfl_down(ssum,off); ssq += __shfl_down(ssq,off); }
  int wid = t >> 6;
  if ((t & 63) == 0){ rs1[wid]=ssum; rs2[wid]=ssq; }
  __syncthreads();
  if (t == 0){
    float a = rs1[0]+rs1[1]+rs1[2]+rs1[3];
    float b = rs2[0]+rs2[1]+rs2[2]+rs2[3];
    float mean = a * (1.f/512.f);
    float var  = b * (1.f/512.f) - mean*mean;
    mv[0]=mean; mv[1]=rsqrtf(var + 1e-5f);
  }
  __syncthreads();
  float mean=mv[0], rstd=mv[1];
  #pragma unroll
  for (int u=0;u<2;u++){
    int e = t + u*256;
    out[(size_t)tok*512 + e] = (vals[u]-mean)*rstd*g2[e] + b2[e];
  }
}

// ---------------------------------------------------------------- launch
extern "C" void kernel_launch(void* const* d_in, const int* in_sizes, int n_in,
                              void* d_out, int out_size, void* d_ws, size_t ws_size,
                              hipStream_t stream) {
  const float* x  = (const float*)d_in[0];
  const float* wq = (const float*)d_in[1];
  const float* wk = (const float*)d_in[2];
  const float* wv = (const float*)d_in[3];
  const float* wo = (const float*)d_in[4];
  const float* hp = (const float*)d_in[5];
  const float* fp = (const float*)d_in[6];
  const float* w1 = (const float*)d_in[7];
  const float* w2 = (const float*)d_in[8];
  const float* g1 = (const float*)d_in[9];
  const float* b1 = (const float*)d_in[10];
  const float* g2 = (const float*)d_in[11];
  const float* b2 = (const float*)d_in[12];
  float* out = (float*)d_out;
  float* ws  = (float*)d_ws;

  // workspace layout (float slots), ~95.3 MB total:
  unsigned short* qkb  = (unsigned short*)(ws);             // [16384][1024] bf16 (33.5MB); reused as Hb half
  float*          x1   = ws + 8388608;                      // [16384][512] f32
  unsigned short* xb   = (unsigned short*)(ws + 16777216);  // [16384][512] bf16 (dead after k1_v32m)
  unsigned short* wqkb = (unsigned short*)(ws + 20971520);  // [1024][512] bf16 (wq scaled ; wk)
  unsigned short* w2b  = (unsigned short*)(ws + 21233664);  // [512][2048] bf16
  unsigned short* v32t = (unsigned short*)(ws + 21757952);  // [8][32][2048] bf16
  float*          fbuf = ws + 22544384;                     // [16384][8] f32
  unsigned short* wo32b= (unsigned short*)(ws + 22675456);  // [512][32] bf16
  float*          cAB  = ws + 22691840;                     // 80 consts (pad to 128)
  float*          mlb  = ws + 22691968;                     // [4][16384][2] f32
  unsigned short* wv32b= (unsigned short*)(ws + 23806080);  // [32][512] bf16 (32KB)
  float*          Opart= ws + 16777216;                     // [4][16384][32] f32 (8MB, overlays dead xb)
  unsigned short* Hb   = (unsigned short*)(ws);             // overlay (qkb dead after k2)

  k0_setup<<<17, 256, 0, stream>>>(hp, fp, wo, cAB, wo32b);
  kc_cast<<<4872, 256, 0, stream>>>(x, wq, wk, w2, wv, xb, wqkb, w2b, wv32b);
  gemm_bt<512,1024,true,8,128><<<1024, 256, 0, stream>>>(xb, wqkb, qkb, 0);
  k1_v32m<<<256, 256, 0, stream>>>(xb, wv32b, v32t);
  k2_attn<<<512, 256, 0, stream>>>(qkb, v32t, Opart, mlb);
  k3_proj_ln<<<512, 256, 0, stream>>>(x, Opart, mlb, wo32b, g1, b1, cAB, x1, fbuf);
  k4a4<<<256, 256, 0, stream>>>(fbuf, w1, Hb, 0);
  gemm_bt<2048,512,false,4,64><<<256, 256, 0, stream>>>(Hb, w2b, out, 0);
  k4a4<<<256, 256, 0, stream>>>(fbuf, w1, Hb, 8192);
  gemm_bt<2048,512,false,4,64><<<256, 256, 0, stream>>>(Hb, w2b, out, 8192);
  k5_ln2<<<16384, 256, 0, stream>>>(x1, g2, b2, out);
}

// Round 9
// 373.807 us; speedup vs baseline: 1.0493x; 1.0493x over previous
//
#include <hip/hip_runtime.h>
#include <hip/hip_bf16.h>
#include <math.h>

// B=8 T=2048 E=512 H=8 | NQ_H=4 NL=2 | NQ_F=8 FFN=2048
// Quantum circuits collapse to: qout_q = cos(x_q)*A_q - sin(x_q)*B_q (per-head/FFN consts).
// Round 16: R15 NaN'd -- bundled V reg-prefetch + v_cvt_pk_bf16_f32 asm; cannot attribute
// blame without counters (garbage bf16 in P operand fits either). REVERT to the validated
// composition: round-13 k2 (QBLK=128 BK=64 direct V-stage f2bf, passed @53us FETCH 32MB)
// + round-14 k3 fused 4-partial merge (passed; same Opart/mlb interface both sides).
// Every kernel here has individually passed the harness in this exact form.

#define B_   8
#define T_   2048
#define E_   512

typedef __attribute__((ext_vector_type(8))) short bf16x8;
typedef __attribute__((ext_vector_type(4))) short bf16x4;
typedef __attribute__((ext_vector_type(4))) float f32x4;

#define GLL16(g, l) __builtin_amdgcn_global_load_lds((const __attribute__((address_space(1))) void*)(g), (__attribute__((address_space(3))) void*)(l), 16, 0, 0)

__device__ inline unsigned short f2bf(float f){
  union { float f; unsigned u; } v; v.f = f;
  unsigned r = v.u + 0x7fff + ((v.u >> 16) & 1);   // RTNE
  return (unsigned short)(r >> 16);
}

// ------------------------------------------- K0 (parallel): circuits + wo32b pack
__global__ __launch_bounds__(256) void k0_setup(const float* __restrict__ hp,
                         const float* __restrict__ fp,
                         const float* __restrict__ wo, float* __restrict__ cAB,
                         unsigned short* __restrict__ wo32b) {
  int t = threadIdx.x, bi = blockIdx.x;
  if (bi > 0) {                      // blocks 1..16: pack wo32b bf16 (coalesced)
    int gid = (bi-1)*256 + t;        // 4096 = 512 rows x 8 groups of 4 cols
    int e = gid >> 3, c4 = gid & 7;  // wo cols c4*64 .. c4*64+3 are contiguous
    float4 v = *(const float4*)(wo + (size_t)e*512 + c4*64);
    unsigned short h[4] = { f2bf(v.x), f2bf(v.y), f2bf(v.z), f2bf(v.w) };
    *(unsigned long long*)(wo32b + (size_t)e*32 + c4*4) = *(unsigned long long*)h;
    return;
  }
  // ---- block 0: FFN 8-qubit circuit, one amplitude per thread ----
  __shared__ float fst[256], tmp[256], ra[256], rb[256];
  fst[t] = (t == 0) ? 1.f : 0.f;
  __syncthreads();
  #pragma unroll
  for (int q = 0; q < 8; ++q) {      // RY layer (params row 0)
    int str = 1 << (7-q);
    float th = 0.5f * fp[q];
    float c = cosf(th), s = sinf(th);
    float self = fst[t], part = fst[t ^ str];
    float nv = (t & str) ? (c*self + s*part) : (c*self - s*part);
    __syncthreads();
    tmp[t] = nv;
    __syncthreads();
    fst[t] = tmp[t];
    __syncthreads();
  }
  #pragma unroll
  for (int g = 0; g < 8; ++g) {      // CNOT chain + ring
    int ctrl = (g < 7) ? g : 7, tgt = (g < 7) ? g+1 : 0;
    int cs = 1 << (7-ctrl), tsr = 1 << (7-tgt);
    float nv = fst[(t & cs) ? (t ^ tsr) : t];
    __syncthreads();
    fst[t] = nv;
    __syncthreads();
  }
  #pragma unroll
  for (int q = 0; q < 8; ++q) {      // <Z_q>, <X_q>
    int str = 1 << (7-q);
    float a = fst[t]*fst[t] * ((t & str) ? -1.f : 1.f);
    float b = fst[t]*fst[t ^ str];
    ra[t] = a; rb[t] = b;
    __syncthreads();
    for (int off = 128; off > 0; off >>= 1){
      if (t < off){ ra[t] += ra[t+off]; rb[t] += rb[t+off]; }
      __syncthreads();
    }
    if (t == 0){ cAB[64+q] = ra[0]; cAB[72+q] = rb[0]; }
    __syncthreads();
  }
  // ---- per-head 4-qubit circuits: 8 parallel threads, 16 amps in registers ----
  if (t < 8) {
    float st[16];
    #pragma unroll
    for (int i=0;i<16;i++) st[i]=0.f;
    st[0]=1.f;
    for (int l=0;l<2;l++){
      for (int q=0;q<4;q++){
        float th = 0.5f*hp[t*8 + l*4 + q];
        float c = cosf(th), s = sinf(th);
        int str = 1<<(3-q);
        for (int i=0;i<16;i++) if (!(i & str)) {
          float s0=st[i], s1=st[i|str];
          st[i]     = c*s0 - s*s1;
          st[i|str] = s*s0 + c*s1;
        }
      }
      for (int q=0;q<4;q++){
        int ctrl = (q<3)? q : 3, tgt = (q<3)? q+1 : 0;
        int cs = 1<<(3-ctrl), tsr = 1<<(3-tgt);
        for (int i=0;i<16;i++) if ((i&cs) && !(i&tsr)) {
          float tt = st[i]; st[i]=st[i|tsr]; st[i|tsr]=tt;
        }
      }
    }
    for (int q=0;q<4;q++){
      int str = 1<<(3-q);
      float A=0.f, Bv=0.f;
      for (int i=0;i<16;i++){
        A  += st[i]*st[i] * ((i&str)? -1.f : 1.f);
        Bv += st[i]*st[i^str];
      }
      cAB[t*4+q]    = A;
      cAB[32+t*4+q] = Bv;
    }
  }
}

// -------------------------- merged casts to bf16 (xb | wqkb, w2b, wv32b)
__global__ __launch_bounds__(256) void kc_cast(const float* __restrict__ x,
                     const float* __restrict__ wq, const float* __restrict__ wk,
                     const float* __restrict__ w2, const float* __restrict__ wv,
                     unsigned short* __restrict__ xb, unsigned short* __restrict__ wqkb,
                     unsigned short* __restrict__ w2b, unsigned short* __restrict__ wv32b){
  int bi = blockIdx.x;
  if (bi < 4096) {                                 // x -> xb: 1048576 chunks of 8
    int i = bi*256 + threadIdx.x;
    const float4* p = (const float4*)x + (size_t)i*2;
    float4 a = p[0], b = p[1];
    union { unsigned short h[8]; uint4 u; } o;
    o.h[0]=f2bf(a.x); o.h[1]=f2bf(a.y); o.h[2]=f2bf(a.z); o.h[3]=f2bf(a.w);
    o.h[4]=f2bf(b.x); o.h[5]=f2bf(b.y); o.h[6]=f2bf(b.z); o.h[7]=f2bf(b.w);
    ((uint4*)xb)[i] = o.u;
    return;
  }
  int i = (bi-4096)*256 + threadIdx.x;             // 198656 chunks of 8
  const float* src; unsigned short* dst; float s = 1.f;
  if (i < 65536){
    int row = i >> 6, c8 = (i & 63)*8;
    if (row < 512){ src = wq + (size_t)row*512 + c8; s = 0.044194173824159216f; } // fold 1/sqrt(E)
    else          { src = wk + (size_t)(row-512)*512 + c8; }
    dst = wqkb + (size_t)row*512 + c8;
  } else if (i < 196608){
    int j = i - 65536;
    src = w2 + (size_t)j*8; dst = w2b + (size_t)j*8;
  } else {
    int j = i - 196608;                            // 2048 chunks: wv32b [32][512]
    int r = j >> 6, c8 = (j & 63)*8;               // channel r = head*4 + qubit
    src = wv + (size_t)((r>>2)*64 + (r&3))*512 + c8;
    dst = wv32b + (size_t)r*512 + c8;
  }
  float4 a = *(const float4*)src, b = *(const float4*)(src+4);
  union { unsigned short h[8]; uint4 u; } o;
  o.h[0]=f2bf(a.x*s); o.h[1]=f2bf(a.y*s); o.h[2]=f2bf(a.z*s); o.h[3]=f2bf(a.w*s);
  o.h[4]=f2bf(b.x*s); o.h[5]=f2bf(b.y*s); o.h[6]=f2bf(b.z*s); o.h[7]=f2bf(b.w*s);
  *(uint4*)dst = o.u;
}

// ------------- m97-style MFMA GEMM: C = A (MxK) * Bw^T (NxK), XCD-aware swizzle
// 1-D grid of GX*GM blocks; same-XCD blocks (lin%8) share A m-tiles via L2.
template<int K, int LDC, bool OUTBF, int GX, int GM>
__global__ __launch_bounds__(256,2) void gemm_bt(
    const unsigned short* __restrict__ A, const unsigned short* __restrict__ Bw,
    void* __restrict__ C, int m_base){
  __shared__ __align__(16) char sm[16384];
  char* As = sm; char* Bs = sm + 8192;             // [128][32] bf16, 64B rows, xor-swizzled
  int t = threadIdx.x, w = t>>6, l = t&63;
  int lr = l&15, quad = l>>4;
  int lin = blockIdx.x;
  int n0 = ((lin >> 3) % GX) * 128;
  int m0 = ((lin & 7) * (GM/8) + lin / (8*GX)) * 128;
  int wr = (w>>1)*64, wc = (w&1)*64;
  f32x4 acc[4][4] = {};
  for (int k0 = 0; k0 < K; k0 += 32){
    __syncthreads();
    #pragma unroll
    for (int c = 0; c < 2; ++c){
      int ch = c*256 + t, row = ch>>2, sw = ch&3, lc = sw ^ ((row>>1)&3);
      GLL16(A  + (size_t)(m0+row)*K + k0 + lc*8, As + c*4096 + w*1024);
      GLL16(Bw + (size_t)(n0+row)*K + k0 + lc*8, Bs + c*4096 + w*1024);
    }
    __syncthreads();
    bf16x8 af[4], bg[4];
    #pragma unroll
    for (int i=0;i<4;++i){
      int ra = wr + i*16 + lr;
      af[i] = *(const bf16x8*)(As + ra*64 + (quad ^ ((ra>>1)&3))*16);
      int rb = wc + i*16 + lr;
      bg[i] = *(const bf16x8*)(Bs + rb*64 + (quad ^ ((rb>>1)&3))*16);
    }
    #pragma unroll
    for (int i=0;i<4;++i)
      #pragma unroll
      for (int j=0;j<4;++j)
        acc[i][j] = __builtin_amdgcn_mfma_f32_16x16x32_bf16(af[i], bg[j], acc[i][j], 0,0,0);
  }
  #pragma unroll
  for (int i=0;i<4;++i)
    #pragma unroll
    for (int j=0;j<4;++j)
      #pragma unroll
      for (int r=0;r<4;++r){
        size_t row = (size_t)(m_base + m0 + wr + i*16 + quad*4 + r);
        int col = n0 + wc + j*16 + lr;
        if constexpr (OUTBF) ((unsigned short*)C)[row*LDC + col] = f2bf(acc[i][j][r]);
        else                 ((float*)C)[row*LDC + col] = acc[i][j][r];
      }
}

// ---- K1v (MFMA): v32t[b][c][s] = bf16(xb @ wv32b^T), skinny N=32 GEMM.
__global__ __launch_bounds__(256) void k1_v32m(const unsigned short* __restrict__ xb,
    const unsigned short* __restrict__ wv32b, unsigned short* __restrict__ v32t){
  __shared__ __align__(16) char sm1[98304];     // Xs 64KB + Ws 32KB
  char* Xs = sm1; char* Ws = sm1 + 65536;
  int t = threadIdx.x, w = t>>6, l = t&63, lr = l&15, quad = l>>4;
  int m0 = blockIdx.x * 64;
  #pragma unroll
  for (int i=0;i<16;++i){                       // stage 16 X subtiles [64][32]
    int p = i*256 + t, ks = p>>8, c2 = p&255, row = c2>>2, swp = c2&3;
    int lc = swp ^ ((row>>1)&3);
    GLL16(xb + (size_t)(m0+row)*512 + ks*32 + lc*8, Xs + (p>>6)*1024);
  }
  #pragma unroll
  for (int i=0;i<8;++i){                        // stage 16 W subtiles [32][32]
    int p = i*256 + t, ks = p>>7, c2 = p&127, row = c2>>2, swp = c2&3;
    int lc = swp ^ ((row>>1)&3);
    GLL16(wv32b + (size_t)row*512 + ks*32 + lc*8, Ws + (p>>6)*1024);
  }
  __syncthreads();
  f32x4 acc[2] = {};
  #pragma unroll
  for (int ks=0; ks<16; ++ks){
    int xrow = w*16 + lr;
    bf16x8 bq = *(const bf16x8*)(Xs + ks*4096 + xrow*64 + (quad ^ ((xrow>>1)&3))*16);
    #pragma unroll
    for (int ni=0; ni<2; ++ni){
      int wrow = ni*16 + lr;
      bf16x8 af = *(const bf16x8*)(Ws + ks*2048 + wrow*64 + (quad ^ ((wrow>>1)&3))*16);
      acc[ni] = __builtin_amdgcn_mfma_f32_16x16x32_bf16(af, bq, acc[ni], 0,0,0);
    }
  }
  int bb = m0 >> 11, sbase = (m0 & 2047) + w*16 + lr;
  #pragma unroll
  for (int ni=0; ni<2; ++ni)
    #pragma unroll
    for (int r=0; r<4; ++r){
      int c = ni*16 + quad*4 + r;
      v32t[((size_t)(bb*32 + c))*2048 + sbase] = f2bf(acc[ni][r]);
    }
}

// ------ K2: MFMA flash attention (S^T trick), QBLK=128, BK=64, XCD-local, KV-split x4
__global__ __launch_bounds__(256,2) void k2_attn(
    const unsigned short* __restrict__ qkb, const unsigned short* __restrict__ v32t,
    float* __restrict__ Opart, float* __restrict__ mlb){
  __shared__ __align__(16) char sm[77824];
  char* Qc  = sm;            // 2 kk sub-blocks [128][32] bf16 swizzled (16 KB)
  char* Ks  = sm + 16384;    // 2 kk sub-blocks [256][32] bf16 swizzled (32 KB)
  char* Vts = sm + 49152;    // [32][256+8] bf16, 528B rows (16.5 KB)
  float* OtL = (float*)sm;           // merge overlay: [4][128][36] f32 (73728 B)
  float* mL  = (float*)(sm + 73728); // [4][128]
  float* lL  = (float*)(sm + 75776); // [4][128]

  int t = threadIdx.x, w = t>>6, l = t&63;
  int lr = l & 15, quad = l >> 4;
  int lin = blockIdx.x;
  int b = lin & 7;                   // one batch per XCD
  int m0 = ((lin >> 3) & 15) * 128;
  int half = lin >> 7;               // KV quarter: s in [half*512, half*512+512)
  size_t bT = (size_t)b*2048;
  const char* qbase = (const char*)qkb + (bT + m0)*2048;       // q cols 0-511 (pre-scaled)
  const char* vbase = (const char*)v32t + (size_t)b*32*4096;

  f32x4 Ot[2][8] = {};
  float mold[8], lsum[8];
  #pragma unroll
  for (int qj=0;qj<8;++qj){ mold[qj] = -1e30f; lsum[qj] = 0.f; }

  for (int st = 0; st < 2; ++st){
    int s0 = (half*2 + st)*256;
    const char* kbase = (const char*)qkb + (bT + s0)*2048 + 1024; // k cols 512-1023
    __syncthreads();
    { // stage V^T tile [32 vcols][256 scols]
      int j = t>>3, seg = t&7;
      const uint4* vs = (const uint4*)(vbase + (size_t)j*4096 + (s0 + seg*32)*2);
      uint4* vd = (uint4*)(Vts + j*528 + seg*64);
      vd[0]=vs[0]; vd[1]=vs[1]; vd[2]=vs[2]; vd[3]=vs[3];
    }
    f32x4 acc[4][8] = {};   // S^T tile: sc = w*64+si*16+quad*4+r, qr = qj*16+lr
    for (int ec = 0; ec < 8; ++ec){  // BK=64: 8 iterations over the 512 K-dim
      __syncthreads();
      #pragma unroll
      for (int u = 0; u < 4; ++u){                               // Q chunks [128][64]
        int kk = u>>1, c = u&1;
        int ch = c*256 + t, row = ch>>2, sw = ch&3, lc = sw ^ ((row>>1)&3);
        GLL16(qbase + (size_t)row*2048 + ec*128 + kk*64 + lc*16,
              Qc + kk*8192 + c*4096 + w*1024);
      }
      #pragma unroll
      for (int rd = 0; rd < 4; ++rd){                            // K chunks [256][64]
        int ch = rd*256 + t, row = ch>>2, sw = ch&3, lc = sw ^ ((row>>1)&3);
        GLL16(kbase + (size_t)row*2048 + ec*128 +      lc*16, Ks +         rd*4096 + w*1024);
        GLL16(kbase + (size_t)row*2048 + ec*128 + 64 + lc*16, Ks + 16384 + rd*4096 + w*1024);
      }
      __syncthreads();
      #pragma unroll
      for (int kk = 0; kk < 2; ++kk){
        bf16x8 af[4];
        #pragma unroll
        for (int si = 0; si < 4; ++si){
          int row = w*64 + si*16 + lr;
          af[si] = *(const bf16x8*)(Ks + kk*16384 + row*64 + (quad ^ ((row>>1)&3))*16);
        }
        #pragma unroll
        for (int qh = 0; qh < 2; ++qh){
          bf16x8 bq[4];
          #pragma unroll
          for (int jj = 0; jj < 4; ++jj){
            int row = (qh*4+jj)*16 + lr;
            bq[jj] = *(const bf16x8*)(Qc + kk*8192 + row*64 + (quad ^ ((row>>1)&3))*16);
          }
          __builtin_amdgcn_s_setprio(1);
          #pragma unroll
          for (int si = 0; si < 4; ++si)
            #pragma unroll
            for (int jj = 0; jj < 4; ++jj)   // S^T = K * Q^T
              acc[si][qh*4+jj] = __builtin_amdgcn_mfma_f32_16x16x32_bf16(af[si], bq[jj], acc[si][qh*4+jj], 0,0,0);
          __builtin_amdgcn_s_setprio(0);
        }
      }
    }
    // online softmax over sc (rows of S^T) + PV from registers
    bf16x4 aV[2][4];
    #pragma unroll
    for (int vt=0; vt<2; ++vt)
      #pragma unroll
      for (int si=0; si<4; ++si)
        aV[vt][si] = *(const bf16x4*)(Vts + (vt*16+lr)*528 + (w*64 + si*16 + quad*4)*2);
    #pragma unroll
    for (int qj=0; qj<8; ++qj){
      float mt = -1e30f;
      #pragma unroll
      for (int si=0; si<4; ++si)
        #pragma unroll
        for (int r=0;r<4;++r) mt = fmaxf(mt, acc[si][qj][r]);
      mt = fmaxf(mt, __shfl_xor(mt, 16));
      mt = fmaxf(mt, __shfl_xor(mt, 32));
      float mn = fmaxf(mold[qj], mt);
      float al = __expf(mold[qj] - mn);
      mold[qj] = mn;
      float rs = 0.f;
      #pragma unroll
      for (int si=0; si<4; ++si)
        #pragma unroll
        for (int r=0;r<4;++r){
          float p = __expf(acc[si][qj][r] - mn);
          acc[si][qj][r] = p; rs += p;
        }
      rs += __shfl_xor(rs, 16); rs += __shfl_xor(rs, 32);
      lsum[qj] = lsum[qj]*al + rs;
      Ot[0][qj] *= al; Ot[1][qj] *= al;
      #pragma unroll
      for (int si=0; si<4; ++si){
        bf16x4 pb;                                  // P^T in exact B-operand layout
        pb[0]=(short)f2bf(acc[si][qj][0]); pb[1]=(short)f2bf(acc[si][qj][1]);
        pb[2]=(short)f2bf(acc[si][qj][2]); pb[3]=(short)f2bf(acc[si][qj][3]);
        Ot[0][qj] = __builtin_amdgcn_mfma_f32_16x16x16bf16_1k(aV[0][si], pb, Ot[0][qj], 0,0,0);
        Ot[1][qj] = __builtin_amdgcn_mfma_f32_16x16x16bf16_1k(aV[1][si], pb, Ot[1][qj], 0,0,0);
      }
    }
  }
  // merge 4 per-wave partial streams -> unnormalized quarter-partials to global
  __syncthreads();
  #pragma unroll
  for (int qj=0; qj<8; ++qj){
    if (quad == 0){ mL[w*128 + qj*16 + lr] = mold[qj]; lL[w*128 + qj*16 + lr] = lsum[qj]; }
    *(f32x4*)(OtL + (size_t)(w*128 + qj*16 + lr)*36 + quad*4)      = Ot[0][qj];
    *(f32x4*)(OtL + (size_t)(w*128 + qj*16 + lr)*36 + 16 + quad*4) = Ot[1][qj];
  }
  __syncthreads();
  #pragma unroll
  for (int u=0; u<2; ++u){
    int qr = u*64 + (t>>2), vg = (t&3)*8;
    float M = -1e30f;
    #pragma unroll
    for (int w4=0; w4<4; ++w4) M = fmaxf(M, mL[w4*128+qr]);
    float L = 0.f; float o[8] = {};
    #pragma unroll
    for (int w4=0; w4<4; ++w4){
      float a = __expf(mL[w4*128+qr] - M);
      L += a * lL[w4*128+qr];
      const float* Op = OtL + (size_t)(w4*128+qr)*36 + vg;
      #pragma unroll
      for (int j=0;j<8;++j) o[j] += a*Op[j];
    }
    size_t tok = bT + m0 + qr;
    float* od = Opart + ((size_t)half*16384 + tok)*32 + vg;
    *(float4*)od     = make_float4(o[0],o[1],o[2],o[3]);
    *(float4*)(od+4) = make_float4(o[4],o[5],o[6],o[7]);
    if ((t&3) == 0){
      mlb[((size_t)half*16384 + tok)*2]     = M;
      mlb[((size_t)half*16384 + tok)*2 + 1] = L;
    }
  }
}

// ---- K3 (MFMA): x1 = LN(x + merge(Opart)@wo32b^T, g1,b1); fbuf = trig(x1[:, :8])
// k2_merge fused into the Qs stage: 4-partial softmax merge + circuit trig inline.
__global__ __launch_bounds__(256) void k3_proj_ln(const float* __restrict__ x,
    const float* __restrict__ Opart, const float* __restrict__ mlb,
    const unsigned short* __restrict__ wo32b,
    const float* __restrict__ g1, const float* __restrict__ b1,
    const float* __restrict__ cAB, float* __restrict__ x1, float* __restrict__ fbuf) {
  __shared__ __align__(16) char sm3[36224];
  char* Ws = sm3;                          // [512][32] bf16 swizzled, 32 KB
  char* Qs = sm3 + 32768;                  // [32][32] bf16 swizzled, 2 KB
  float* red1 = (float*)(sm3 + 34816);     // [4][32]
  float* red2 = (float*)(sm3 + 35328);     // [4][32]
  float* mm   = (float*)(sm3 + 35840);     // [32]
  float* rr   = (float*)(sm3 + 35968);     // [32]
  int t = threadIdx.x, w = t>>6, l = t&63, lr = l&15, quad = l>>4;
  int tok0 = blockIdx.x * 32;
  #pragma unroll
  for (int i=0;i<8;++i){                   // stage wo32b: 2048 uint4
    int g = t + i*256, row = g>>2, ch = g&3;
    uint4 v = ((const uint4*)wo32b)[g];
    *(uint4*)(Ws + row*64 + (ch ^ ((row>>1)&3))*16) = v;
  }
  { // fused merge: Qs[tok][col] = trig(softmax-merge of 4 Opart streams)
    int tokL = t>>3, cg = t&7;             // 32 tokens x 8 col-groups of 4
    size_t gt = (size_t)tok0 + tokL;
    float m[4], lv[4];
    #pragma unroll
    for (int h=0;h<4;++h){
      m[h]  = mlb[((size_t)h*16384 + gt)*2];
      lv[h] = mlb[((size_t)h*16384 + gt)*2 + 1];
    }
    float M = fmaxf(fmaxf(m[0],m[1]), fmaxf(m[2],m[3]));
    float a[4], L = 0.f;
    #pragma unroll
    for (int h=0;h<4;++h){ a[h] = __expf(m[h]-M); L += a[h]*lv[h]; }
    float inv = 1.f / L;
    float o[4] = {};
    #pragma unroll
    for (int h=0;h<4;++h){
      float4 v = *(const float4*)(Opart + ((size_t)h*16384 + gt)*32 + cg*4);
      o[0] += a[h]*v.x; o[1] += a[h]*v.y; o[2] += a[h]*v.z; o[3] += a[h]*v.w;
    }
    bf16x4 qv;
    #pragma unroll
    for (int j=0;j<4;++j){
      float ov = o[j] * inv;
      int cc = cg*4 + j;
      qv[j] = (short)f2bf(cosf(ov)*cAB[cc] - sinf(ov)*cAB[32+cc]);
    }
    *(bf16x4*)(Qs + tokL*64 + (((cg>>1) ^ ((tokL>>1)&3))<<4) + ((cg&1)<<3)) = qv;
  }
  __syncthreads();
  bf16x8 af[2], bf[8];
  #pragma unroll
  for (int i=0;i<2;++i){
    int m = i*16 + lr;
    af[i] = *(const bf16x8*)(Qs + m*64 + (quad ^ ((m>>1)&3))*16);
  }
  #pragma unroll
  for (int j=0;j<8;++j){
    int n = w*128 + j*16 + lr;
    bf[j] = *(const bf16x8*)(Ws + n*64 + (quad ^ ((n>>1)&3))*16);
  }
  f32x4 acc[2][8];
  #pragma unroll
  for (int i=0;i<2;++i)
    #pragma unroll
    for (int j=0;j<8;++j){
      f32x4 z = {0.f,0.f,0.f,0.f};
      acc[i][j] = __builtin_amdgcn_mfma_f32_16x16x32_bf16(af[i], bf[j], z, 0,0,0);
    }
  // residual add + row-sum accumulation
  float s1[2][4] = {}, s2[2][4] = {};
  #pragma unroll
  for (int i=0;i<2;++i)
    #pragma unroll
    for (int r=0;r<4;++r){
      int m = i*16 + quad*4 + r;
      const float* xrow = x + (size_t)(tok0+m)*512 + w*128 + lr;
      #pragma unroll
      for (int j=0;j<8;++j){
        float v = acc[i][j][r] + xrow[j*16];
        acc[i][j][r] = v;
        s1[i][r] += v; s2[i][r] += v*v;
      }
    }
  #pragma unroll
  for (int off=1; off<16; off<<=1){
    #pragma unroll
    for (int i=0;i<2;++i)
      #pragma unroll
      for (int r=0;r<4;++r){
        s1[i][r] += __shfl_xor(s1[i][r], off);
        s2[i][r] += __shfl_xor(s2[i][r], off);
      }
  }
  if (lr == 0){
    #pragma unroll
    for (int i=0;i<2;++i)
      #pragma unroll
      for (int r=0;r<4;++r){
        int m = i*16 + quad*4 + r;
        red1[w*32 + m] = s1[i][r];
        red2[w*32 + m] = s2[i][r];
      }
  }
  __syncthreads();
  if (t < 32){
    float a = red1[t] + red1[32+t] + red1[64+t] + red1[96+t];
    float bb = red2[t] + red2[32+t] + red2[64+t] + red2[96+t];
    float mean = a * (1.f/512.f);
    float var  = bb * (1.f/512.f) - mean*mean;
    mm[t] = mean; rr[t] = rsqrtf(var + 1e-5f);
  }
  __syncthreads();
  float g1v[8], b1v[8];
  #pragma unroll
  for (int j=0;j<8;++j){
    int n = w*128 + j*16 + lr;
    g1v[j] = g1[n]; b1v[j] = b1[n];
  }
  #pragma unroll
  for (int i=0;i<2;++i)
    #pragma unroll
    for (int r=0;r<4;++r){
      int m = i*16 + quad*4 + r;
      float mean = mm[m], rstd = rr[m];
      float* orow = x1 + (size_t)(tok0+m)*512 + w*128 + lr;
      #pragma unroll
      for (int j=0;j<8;++j){
        float nv = (acc[i][j][r]-mean)*rstd*g1v[j] + b1v[j];
        orow[j*16] = nv;
        if (w == 0 && j == 0 && lr < 8)
          fbuf[(size_t)(tok0+m)*8 + lr] = cosf(nv)*cAB[64+lr] - sinf(nv)*cAB[72+lr];
      }
    }
}

// ---- K4a4: Hb = bf16(relu(fbuf @ w1^T)) for an 8192-token half.
__global__ __launch_bounds__(256) void k4a4(const float* __restrict__ fbuf,
    const float* __restrict__ w1, unsigned short* __restrict__ Hb, int row0){
  __shared__ float w1s[16384];                // [2048][8] f32 linear, 64KB
  int t = threadIdx.x;
  #pragma unroll
  for (int i=0;i<16;++i){                     // coalesced stage: 4096 float4
    int p = i*256 + t;
    *(float4*)(w1s + (size_t)p*4) = *(const float4*)(w1 + (size_t)p*4);
  }
  __syncthreads();
  float wv[8][8];                             // rows 8t..8t+7 -> 64 VGPRs
  #pragma unroll
  for (int i=0;i<16;++i){
    float4 v = *(const float4*)(w1s + t*64 + i*4);
    wv[i>>1][(i&1)*4+0]=v.x; wv[i>>1][(i&1)*4+1]=v.y;
    wv[i>>1][(i&1)*4+2]=v.z; wv[i>>1][(i&1)*4+3]=v.w;
  }
  int tokL = blockIdx.x * 32;                 // local token base within the half
  #pragma unroll 2
  for (int u=0;u<32;++u){
    const float4* fp4 = (const float4*)(fbuf + (size_t)(row0 + tokL + u)*8);
    float4 fa = fp4[0], fb = fp4[1];
    union { unsigned short h[8]; uint4 q; } o;
    #pragma unroll
    for (int j=0;j<8;++j){
      float s = fa.x*wv[j][0] + fa.y*wv[j][1] + fa.z*wv[j][2] + fa.w*wv[j][3]
              + fb.x*wv[j][4] + fb.y*wv[j][5] + fb.z*wv[j][6] + fb.w*wv[j][7];
      o.h[j] = f2bf(fmaxf(s, 0.f));
    }
    *(uint4*)(Hb + (size_t)(tokL + u)*2048 + t*8) = o.q;
  }
}

// --------------------------------------------- K5: out = LN(x1 + out2, g2, b2)
__global__ __launch_bounds__(256) void k5_ln2(const float* __restrict__ x1,
    const float* __restrict__ g2, const float* __restrict__ b2,
    float* __restrict__ out) {
  int tok = blockIdx.x, t = threadIdx.x;
  __shared__ float rs1[4], rs2[4], mv[2];
  float vals[2], ssum=0.f, ssq=0.f;
  #pragma unroll
  for (int u=0;u<2;u++){
    int e = t + u*256;
    float s = x1[(size_t)tok*512 + e] + out[(size_t)tok*512 + e];
    vals[u]=s; ssum+=s; ssq+=s*s;
  }
  #pragma unroll
  for (int off=32; off>0; off>>=1){ ssum += __shfl_down(ssum,off); ssq += __shfl_down(ssq,off); }
  int wid = t >> 6;
  if ((t & 63) == 0){ rs1[wid]=ssum; rs2[wid]=ssq; }
  __syncthreads();
  if (t == 0){
    float a = rs1[0]+rs1[1]+rs1[2]+rs1[3];
    float b = rs2[0]+rs2[1]+rs2[2]+rs2[3];
    float mean = a * (1.f/512.f);
    float var  = b * (1.f/512.f) - mean*mean;
    mv[0]=mean; mv[1]=rsqrtf(var + 1e-5f);
  }
  __syncthreads();
  float mean=mv[0], rstd=mv[1];
  #pragma unroll
  for (int u=0;u<2;u++){
    int e = t + u*256;
    out[(size_t)tok*512 + e] = (vals[u]-mean)*rstd*g2[e] + b2[e];
  }
}

// ---------------------------------------------------------------- launch
extern "C" void kernel_launch(void* const* d_in, const int* in_sizes, int n_in,
                              void* d_out, int out_size, void* d_ws, size_t ws_size,
                              hipStream_t stream) {
  const float* x  = (const float*)d_in[0];
  const float* wq = (const float*)d_in[1];
  const float* wk = (const float*)d_in[2];
  const float* wv = (const float*)d_in[3];
  const float* wo = (const float*)d_in[4];
  const float* hp = (const float*)d_in[5];
  const float* fp = (const float*)d_in[6];
  const float* w1 = (const float*)d_in[7];
  const float* w2 = (const float*)d_in[8];
  const float* g1 = (const float*)d_in[9];
  const float* b1 = (const float*)d_in[10];
  const float* g2 = (const float*)d_in[11];
  const float* b2 = (const float*)d_in[12];
  float* out = (float*)d_out;
  float* ws  = (float*)d_ws;

  // workspace layout (float slots), ~95.3 MB total:
  unsigned short* qkb  = (unsigned short*)(ws);             // [16384][1024] bf16 (33.5MB); reused as Hb half
  float*          x1   = ws + 8388608;                      // [16384][512] f32
  unsigned short* xb   = (unsigned short*)(ws + 16777216);  // [16384][512] bf16 (dead after k1_v32m)
  unsigned short* wqkb = (unsigned short*)(ws + 20971520);  // [1024][512] bf16 (wq scaled ; wk)
  unsigned short* w2b  = (unsigned short*)(ws + 21233664);  // [512][2048] bf16
  unsigned short* v32t = (unsigned short*)(ws + 21757952);  // [8][32][2048] bf16
  float*          fbuf = ws + 22544384;                     // [16384][8] f32
  unsigned short* wo32b= (unsigned short*)(ws + 22675456);  // [512][32] bf16
  float*          cAB  = ws + 22691840;                     // 80 consts (pad to 128)
  float*          mlb  = ws + 22691968;                     // [4][16384][2] f32
  unsigned short* wv32b= (unsigned short*)(ws + 23806080);  // [32][512] bf16 (32KB)
  float*          Opart= ws + 16777216;                     // [4][16384][32] f32 (8MB, overlays dead xb)
  unsigned short* Hb   = (unsigned short*)(ws);             // overlay (qkb dead after k2)

  k0_setup<<<17, 256, 0, stream>>>(hp, fp, wo, cAB, wo32b);
  kc_cast<<<4872, 256, 0, stream>>>(x, wq, wk, w2, wv, xb, wqkb, w2b, wv32b);
  gemm_bt<512,1024,true,8,128><<<1024, 256, 0, stream>>>(xb, wqkb, qkb, 0);
  k1_v32m<<<256, 256, 0, stream>>>(xb, wv32b, v32t);
  k2_attn<<<512, 256, 0, stream>>>(qkb, v32t, Opart, mlb);
  k3_proj_ln<<<512, 256, 0, stream>>>(x, Opart, mlb, wo32b, g1, b1, cAB, x1, fbuf);
  k4a4<<<256, 256, 0, stream>>>(fbuf, w1, Hb, 0);
  gemm_bt<2048,512,false,4,64><<<256, 256, 0, stream>>>(Hb, w2b, out, 0);
  k4a4<<<256, 256, 0, stream>>>(fbuf, w1, Hb, 8192);
  gemm_bt<2048,512,false,4,64><<<256, 256, 0, stream>>>(Hb, w2b, out, 8192);
  k5_ln2<<<16384, 256, 0, stream>>>(x1, g2, b2, out);
}